// Round 8
// baseline (334.150 us; speedup 1.0000x reference)
//
#include <hip/hip_runtime.h>

#define N_NODES 50000
#define N_EDGES 800000
#define HIDDEN  128
#define BN_EPS  1e-5f

typedef __attribute__((ext_vector_type(8))) short short8;
typedef __attribute__((ext_vector_type(8))) unsigned short ushort8;
typedef __attribute__((ext_vector_type(4))) float f32x4;

// round-to-nearest-even fp32 -> bf16 bits
__device__ inline unsigned short f2bf(float x) {
    unsigned u = __float_as_uint(x);
    return (unsigned short)((u + 0x7FFFu + ((u >> 16) & 1u)) >> 16);
}
__device__ inline float bf2f(unsigned short u) {
    return __uint_as_float(((unsigned)u) << 16);
}
// split x into hi (bf16) + residual lo (bf16)
__device__ inline void cvt8(const float* x, short8& hi, short8& lo) {
#pragma unroll
    for (int i = 0; i < 8; i++) {
        unsigned u = __float_as_uint(x[i]);
        unsigned r = (u + 0x7FFFu + ((u >> 16) & 1u)) & 0xFFFF0000u;
        hi[i] = (short)(r >> 16);
        lo[i] = (short)f2bf(x[i] - __uint_as_float(r));
    }
}

#define NB_EDGE 3125   // 3125*256 = 800000 exactly
#define NB_HB   3125   // 6.4M elems / (256 thr * 8) = 3125 exactly
#define NB_W    128    // 128*256 = 32768 = 128*256 W entries

// ---- prep: dst histogram + h->bf16 copy + W->bf16 hi/lo + bn_acc zero -------
__global__ __launch_bounds__(256) void prep_kernel(
    const int* __restrict__ edge_index,
    const float* __restrict__ h,
    const float* __restrict__ W_l,
    const float* __restrict__ W_r,
    int* __restrict__ cnt,
    unsigned short* __restrict__ hb,     // [50000][128] bf16
    unsigned short* __restrict__ WhiG,   // [128 col][256 k]
    unsigned short* __restrict__ WloG,
    float* __restrict__ bn_acc)
{
    const int b = blockIdx.x;
    const int tid = threadIdx.x;
    if (b < NB_EDGE) {
        const int e = b * 256 + tid;                       // < 800000 exact
        atomicAdd(&cnt[edge_index[N_EDGES + e]], 1);
    } else if (b < NB_EDGE + NB_HB) {
        if (b == NB_EDGE) bn_acc[tid] = 0.0f;              // covers 256 floats
        const size_t i8 = ((size_t)(b - NB_EDGE) * 256 + tid) * 8;
        const float4 p0 = *reinterpret_cast<const float4*>(h + i8);
        const float4 p1 = *reinterpret_cast<const float4*>(h + i8 + 4);
        ushort8 v;
        v[0] = f2bf(p0.x); v[1] = f2bf(p0.y); v[2] = f2bf(p0.z); v[3] = f2bf(p0.w);
        v[4] = f2bf(p1.x); v[5] = f2bf(p1.y); v[6] = f2bf(p1.z); v[7] = f2bf(p1.w);
        *reinterpret_cast<ushort8*>(hb + i8) = v;
    } else {
        const int gid = (b - NB_EDGE - NB_HB) * 256 + tid; // < 32768
        const int n = gid >> 8;
        const int k = gid & 255;
        const float w = (k < 128) ? W_l[n * 128 + k] : W_r[n * 128 + (k - 128)];
        unsigned u = __float_as_uint(w);
        unsigned r = (u + 0x7FFFu + ((u >> 16) & 1u)) & 0xFFFF0000u;
        WhiG[gid] = (unsigned short)(r >> 16);
        WloG[gid] = f2bf(w - __uint_as_float(r));
    }
}

// ---- scan: exclusive prefix over cnt -> row_ptr (single block, 1024 thr) ----
__global__ __launch_bounds__(1024) void scan_kernel(
    const int* __restrict__ cnt,
    int* __restrict__ rp)
{
    const int C = 49;                      // 1024*49 = 50176 >= 50000
    const int t = threadIdx.x;
    const int base = t * C;
    int s = 0;
    for (int i = 0; i < C; i++) {
        const int idx = base + i;
        if (idx < N_NODES) s += cnt[idx];
    }
    __shared__ int ps[1024];
    ps[t] = s;
    __syncthreads();
    for (int off = 1; off < 1024; off <<= 1) {
        const int v = (t >= off) ? ps[t - off] : 0;
        __syncthreads();
        ps[t] += v;
        __syncthreads();
    }
    int run = (t > 0) ? ps[t - 1] : 0;     // exclusive prefix of this chunk
    if (t == 1023) rp[N_NODES] = run;      // base=50127 >= N -> run == total
    for (int i = 0; i < C; i++) {
        const int idx = base + i;
        if (idx < N_NODES) { rp[idx] = run; run += cnt[idx]; }
    }
}

// ---- place: csr[rp[d] + cursor[d]++] = src  (cnt reused as cursor) ----------
__global__ __launch_bounds__(256) void place_kernel(
    const int* __restrict__ edge_index,
    const int* __restrict__ rp,
    int* __restrict__ cur,
    unsigned short* __restrict__ csr)
{
    const int e = blockIdx.x * 256 + threadIdx.x;          // < 800000 exact
    const int d = edge_index[N_EDGES + e];
    const int s = edge_index[e];
    const int pos = atomicAdd(&cur[d], 1);
    csr[rp[d] + pos] = (unsigned short)s;
}

// ---- gather: 4 nodes/wave x 16 lanes x ushort8 (full bf16 row per load) -----
__global__ __launch_bounds__(256) void gather_kernel(
    const unsigned short* __restrict__ hb,
    const int* __restrict__ rp,
    const unsigned short* __restrict__ csr,
    unsigned short* __restrict__ aggb)
{
    const int group = (threadIdx.x >> 4) & 3;
    const int sub   = threadIdx.x & 15;
    const int wave  = (blockIdx.x * 256 + threadIdx.x) >> 6;
    const int n = wave * 4 + group;
    if (n >= N_NODES) return;

    const int base = rp[n];
    const int c = rp[n + 1] - base;
    const int fo = sub * 8;

    float acc[8];
#pragma unroll
    for (int i = 0; i < 8; i++) acc[i] = 0.0f;

    int j = 0;
    for (; j + 4 <= c; j += 4) {
        const int s0 = csr[base + j],     s1 = csr[base + j + 1];
        const int s2 = csr[base + j + 2], s3 = csr[base + j + 3];
        const ushort8 v0 = *reinterpret_cast<const ushort8*>(hb + (size_t)s0 * HIDDEN + fo);
        const ushort8 v1 = *reinterpret_cast<const ushort8*>(hb + (size_t)s1 * HIDDEN + fo);
        const ushort8 v2 = *reinterpret_cast<const ushort8*>(hb + (size_t)s2 * HIDDEN + fo);
        const ushort8 v3 = *reinterpret_cast<const ushort8*>(hb + (size_t)s3 * HIDDEN + fo);
#pragma unroll
        for (int i = 0; i < 8; i++)
            acc[i] += (bf2f(v0[i]) + bf2f(v1[i])) + (bf2f(v2[i]) + bf2f(v3[i]));
    }
    for (; j < c; j++) {
        const ushort8 v0 = *reinterpret_cast<const ushort8*>(hb + (size_t)csr[base + j] * HIDDEN + fo);
#pragma unroll
        for (int i = 0; i < 8; i++) acc[i] += bf2f(v0[i]);
    }
    const float inv = 1.0f / (float)((c > 0) ? c : 1);
    ushort8 o;
#pragma unroll
    for (int i = 0; i < 8; i++) o[i] = f2bf(acc[i] * inv);
    *reinterpret_cast<ushort8*>(aggb + (size_t)n * HIDDEN + fo) = o;
}

// ---- MFMA dual GEMM + fused BN stats ----------------------------------------
// out = aggb@W_l^T + b_l + h@W_r^T.  aggb is bf16 (2 MFMAs: ahi*bhi + ahi*blo);
// h half uses split-bf16 3-product. W in LDS hi/lo, XOR slot swizzle.
__global__ __launch_bounds__(256) void gemm_kernel(
    const unsigned short* __restrict__ aggb,
    const float* __restrict__ h,
    const unsigned short* __restrict__ WhiG,   // [128][256]
    const unsigned short* __restrict__ WloG,
    const float* __restrict__ b_l,
    float* __restrict__ out,
    float* __restrict__ bn_acc)
{
    __shared__ short WsH[128][64];
    __shared__ short WsL[128][64];
    __shared__ float bnS[128];
    __shared__ float bnS2[128];

    const int tid  = threadIdx.x;
    const int lane = tid & 63;
    const int wv   = tid >> 6;
    const int row0 = blockIdx.x * 128;
    const int colb = lane & 15;
    const int quad = lane >> 4;

    if (tid < 128) { bnS[tid] = 0.0f; bnS2[tid] = 0.0f; }

    f32x4 acc[2][8];
#pragma unroll
    for (int s = 0; s < 2; s++)
#pragma unroll
        for (int c = 0; c < 8; c++) acc[s][c] = (f32x4)(0.0f);

    const int wcol  = tid >> 1;
    const int sbase = (tid & 1) * 4;

    for (int kc = 0; kc < 4; kc++) {
        const int kb = (kc & 1) * 64;
        const int kw = kc * 64;

        __syncthreads();
#pragma unroll
        for (int j = 0; j < 4; j++) {
            const int slot = sbase + j;
            short8 vh = *reinterpret_cast<const short8*>(WhiG + (size_t)wcol * 256 + kw + slot * 8);
            short8 vl = *reinterpret_cast<const short8*>(WloG + (size_t)wcol * 256 + kw + slot * 8);
            const int sp = slot ^ (wcol & 7);
            *reinterpret_cast<short8*>(&WsH[wcol][sp * 8]) = vh;
            *reinterpret_cast<short8*>(&WsL[wcol][sp * 8]) = vl;
        }
        __syncthreads();

#pragma unroll
        for (int ks = 0; ks < 2; ks++) {
            short8 ahi[2], alo[2];
#pragma unroll
            for (int sub = 0; sub < 2; sub++) {
                int row = row0 + wv * 32 + sub * 16 + colb;
                row = (row < N_NODES) ? row : (N_NODES - 1);
                if (kc < 2) {
                    ahi[sub] = *reinterpret_cast<const short8*>(
                        aggb + (size_t)row * HIDDEN + kb + ks * 32 + quad * 8);
                } else {
                    const float* xp = h + (size_t)row * HIDDEN + kb + ks * 32 + quad * 8;
                    float xr[8];
                    const float4 p0 = *reinterpret_cast<const float4*>(xp);
                    const float4 p1 = *reinterpret_cast<const float4*>(xp + 4);
                    xr[0] = p0.x; xr[1] = p0.y; xr[2] = p0.z; xr[3] = p0.w;
                    xr[4] = p1.x; xr[5] = p1.y; xr[6] = p1.z; xr[7] = p1.w;
                    cvt8(xr, ahi[sub], alo[sub]);
                }
            }
#pragma unroll
            for (int c = 0; c < 8; c++) {
                const int bc = c * 16 + colb;
                const int sp = (ks * 4 + quad) ^ (bc & 7);
                short8 bhi = *reinterpret_cast<const short8*>(&WsH[bc][sp * 8]);
                short8 blo = *reinterpret_cast<const short8*>(&WsL[bc][sp * 8]);
#pragma unroll
                for (int sub = 0; sub < 2; sub++) {
                    acc[sub][c] = __builtin_amdgcn_mfma_f32_16x16x32_bf16(ahi[sub], bhi, acc[sub][c], 0, 0, 0);
                    acc[sub][c] = __builtin_amdgcn_mfma_f32_16x16x32_bf16(ahi[sub], blo, acc[sub][c], 0, 0, 0);
                    if (kc >= 2)
                        acc[sub][c] = __builtin_amdgcn_mfma_f32_16x16x32_bf16(alo[sub], bhi, acc[sub][c], 0, 0, 0);
                }
            }
        }
    }

#pragma unroll
    for (int c = 0; c < 8; c++) {
        const int col = c * 16 + colb;
        const float bias = b_l[col];
        float s = 0.0f, s2 = 0.0f;
#pragma unroll
        for (int sub = 0; sub < 2; sub++) {
            const int rbase = row0 + wv * 32 + sub * 16 + quad * 4;
#pragma unroll
            for (int reg = 0; reg < 4; reg++) {
                const int r = rbase + reg;
                if (r < N_NODES) {
                    const float o = acc[sub][c][reg] + bias;
                    out[(size_t)r * HIDDEN + col] = o;
                    s += o; s2 += o * o;
                }
            }
        }
        atomicAdd(&bnS[col], s);
        atomicAdd(&bnS2[col], s2);
    }
    __syncthreads();
    if (tid < 128) {
        atomicAdd(&bn_acc[tid], bnS[tid]);
        atomicAdd(&bn_acc[128 + tid], bnS2[tid]);
    }
}

// ---- BN apply + ReLU + residual ----
__global__ __launch_bounds__(256) void bn_apply_kernel(
    const float* __restrict__ h,
    const float* __restrict__ gamma,
    const float* __restrict__ beta,
    const float* __restrict__ bn_acc,
    float* __restrict__ out)
{
    const float inv_n = 1.0f / (float)N_NODES;
    const size_t total = (size_t)N_NODES * HIDDEN;
    size_t idx = ((size_t)blockIdx.x * blockDim.x + threadIdx.x) * 4;
    const size_t stride = (size_t)gridDim.x * blockDim.x * 4;

    for (; idx < total; idx += stride) {
        const int col = (int)(idx & (HIDDEN - 1));
        float4 x  = *reinterpret_cast<float4*>(out + idx);
        float4 sm = *reinterpret_cast<const float4*>(bn_acc + col);
        float4 sq = *reinterpret_cast<const float4*>(bn_acc + HIDDEN + col);
        float4 g  = *reinterpret_cast<const float4*>(gamma + col);
        float4 bt = *reinterpret_cast<const float4*>(beta + col);
        float4 hr = *reinterpret_cast<const float4*>(h + idx);

        float4 res;
        {
            float m = sm.x * inv_n; float var = sq.x * inv_n - m * m;
            float v = g.x * (x.x - m) * rsqrtf(var + BN_EPS) + bt.x;
            res.x = fmaxf(v, 0.0f) + hr.x;
        }
        {
            float m = sm.y * inv_n; float var = sq.y * inv_n - m * m;
            float v = g.y * (x.y - m) * rsqrtf(var + BN_EPS) + bt.y;
            res.y = fmaxf(v, 0.0f) + hr.y;
        }
        {
            float m = sm.z * inv_n; float var = sq.z * inv_n - m * m;
            float v = g.z * (x.z - m) * rsqrtf(var + BN_EPS) + bt.z;
            res.z = fmaxf(v, 0.0f) + hr.z;
        }
        {
            float m = sm.w * inv_n; float var = sq.w * inv_n - m * m;
            float v = g.w * (x.w - m) * rsqrtf(var + BN_EPS) + bt.w;
            res.w = fmaxf(v, 0.0f) + hr.w;
        }
        *reinterpret_cast<float4*>(out + idx) = res;
    }
}

extern "C" void kernel_launch(void* const* d_in, const int* in_sizes, int n_in,
                              void* d_out, int out_size, void* d_ws, size_t ws_size,
                              hipStream_t stream)
{
    const float* h          = (const float*)d_in[0];
    const int*   edge_index = (const int*)d_in[1];
    const float* W_l        = (const float*)d_in[2];
    const float* b_l        = (const float*)d_in[3];
    const float* W_r        = (const float*)d_in[4];
    const float* gamma      = (const float*)d_in[5];
    const float* beta       = (const float*)d_in[6];
    float* out = (float*)d_out;

    char* ws = (char*)d_ws;                                 // all 16B-aligned segments
    int* cnt = (int*)ws;                                    // 50000
    int* rp  = cnt + 50000;                                 // 50004 (uses 50001)
    unsigned short* csr  = (unsigned short*)(rp + 50004);   // 800000
    unsigned short* hb   = csr + 800000;                    // 6,400,000
    unsigned short* aggb = hb + 6400000;                    // 6,400,000
    unsigned short* WhiG = aggb + 6400000;                  // 32768
    unsigned short* WloG = WhiG + 32768;                    // 32768
    float* bn_acc = (float*)(WloG + 32768);                 // 256

    hipMemsetAsync(cnt, 0, 50000 * sizeof(int), stream);

    prep_kernel<<<NB_EDGE + NB_HB + NB_W, 256, 0, stream>>>(
        edge_index, h, W_l, W_r, cnt, hb, WhiG, WloG, bn_acc);

    scan_kernel<<<1, 1024, 0, stream>>>(cnt, rp);

    hipMemsetAsync(cnt, 0, 50000 * sizeof(int), stream);    // reuse cnt as cursor

    place_kernel<<<NB_EDGE, 256, 0, stream>>>(edge_index, rp, cnt, csr);

    gather_kernel<<<(N_NODES / 4 + 3) / 4, 256, 0, stream>>>(hb, rp, csr, aggb);

    gemm_kernel<<<(N_NODES + 127) / 128, 256, 0, stream>>>(
        aggb, h, WhiG, WloG, b_l, out, bn_acc);

    bn_apply_kernel<<<2048, 256, 0, stream>>>(h, gamma, beta, bn_acc, out);
}

// Round 9
// 250.440 us; speedup vs baseline: 1.3343x; 1.3343x over previous
//
#include <hip/hip_runtime.h>

#define N_NODES 50000
#define N_EDGES 800000
#define HIDDEN  128
#define BN_EPS  1e-5f

typedef __attribute__((ext_vector_type(8))) short short8;
typedef __attribute__((ext_vector_type(8))) unsigned short ushort8;
typedef __attribute__((ext_vector_type(4))) float f32x4;

#define NBS 196        // scan blocks: 196*256 = 50176 >= 50000

// round-to-nearest-even fp32 -> bf16 bits
__device__ inline unsigned short f2bf(float x) {
    unsigned u = __float_as_uint(x);
    return (unsigned short)((u + 0x7FFFu + ((u >> 16) & 1u)) >> 16);
}
__device__ inline float bf2f(unsigned short u) {
    return __uint_as_float(((unsigned)u) << 16);
}
// split x into hi (bf16) + residual lo (bf16)
__device__ inline void cvt8(const float* x, short8& hi, short8& lo) {
#pragma unroll
    for (int i = 0; i < 8; i++) {
        unsigned u = __float_as_uint(x[i]);
        unsigned r = (u + 0x7FFFu + ((u >> 16) & 1u)) & 0xFFFF0000u;
        hi[i] = (short)(r >> 16);
        lo[i] = (short)f2bf(x[i] - __uint_as_float(r));
    }
}

#define NB_EDGE 3125   // 3125*256 = 800000 exactly
#define NB_HB   3125   // 6.4M elems / (256 thr * 8) = 3125 exactly
#define NB_W    128    // 128*256 = 32768 W entries

// ---- prep: dst histogram + h->bf16 copy + W->bf16 hi/lo + bn_acc zero -------
__global__ __launch_bounds__(256) void prep_kernel(
    const int* __restrict__ edge_index,
    const float* __restrict__ h,
    const float* __restrict__ W_l,
    const float* __restrict__ W_r,
    int* __restrict__ cnt,
    unsigned short* __restrict__ hb,     // [50000][128] bf16
    unsigned short* __restrict__ WhiG,   // [128 col][256 k]
    unsigned short* __restrict__ WloG,
    float* __restrict__ bn_acc)
{
    const int b = blockIdx.x;
    const int tid = threadIdx.x;
    if (b < NB_EDGE) {
        const int e = b * 256 + tid;                       // < 800000 exact
        atomicAdd(&cnt[edge_index[N_EDGES + e]], 1);
    } else if (b < NB_EDGE + NB_HB) {
        if (b == NB_EDGE) bn_acc[tid] = 0.0f;              // covers 256 floats
        const size_t i8 = ((size_t)(b - NB_EDGE) * 256 + tid) * 8;
        const float4 p0 = *reinterpret_cast<const float4*>(h + i8);
        const float4 p1 = *reinterpret_cast<const float4*>(h + i8 + 4);
        ushort8 v;
        v[0] = f2bf(p0.x); v[1] = f2bf(p0.y); v[2] = f2bf(p0.z); v[3] = f2bf(p0.w);
        v[4] = f2bf(p1.x); v[5] = f2bf(p1.y); v[6] = f2bf(p1.z); v[7] = f2bf(p1.w);
        *reinterpret_cast<ushort8*>(hb + i8) = v;
    } else {
        const int gid = (b - NB_EDGE - NB_HB) * 256 + tid; // < 32768
        const int n = gid >> 8;
        const int k = gid & 255;
        const float w = (k < 128) ? W_l[n * 128 + k] : W_r[n * 128 + (k - 128)];
        unsigned u = __float_as_uint(w);
        unsigned r = (u + 0x7FFFu + ((u >> 16) & 1u)) & 0xFFFF0000u;
        WhiG[gid] = (unsigned short)(r >> 16);
        WloG[gid] = f2bf(w - __uint_as_float(r));
    }
}

// ---- scan phase 1: per-block sums of cnt (256 nodes per block) --------------
__global__ __launch_bounds__(256) void scan1_kernel(
    const int* __restrict__ cnt,
    int* __restrict__ bsum)
{
    const int t = threadIdx.x;
    const int idx = blockIdx.x * 256 + t;
    int v = (idx < N_NODES) ? cnt[idx] : 0;
    __shared__ int ps[256];
    ps[t] = v;
    __syncthreads();
    for (int off = 128; off > 0; off >>= 1) {
        if (t < off) ps[t] += ps[t + off];
        __syncthreads();
    }
    if (t == 0) bsum[blockIdx.x] = ps[0];
}

// ---- scan phase 2: 1 block scans the 196 block sums -> exclusive offsets ----
__global__ __launch_bounds__(256) void scan2_kernel(
    const int* __restrict__ bsum,
    int* __restrict__ boff,
    int* __restrict__ rp)
{
    const int t = threadIdx.x;
    int v = (t < NBS) ? bsum[t] : 0;
    __shared__ int ps[256];
    ps[t] = v;
    __syncthreads();
    for (int off = 1; off < 256; off <<= 1) {
        const int u = (t >= off) ? ps[t - off] : 0;
        __syncthreads();
        ps[t] += u;
        __syncthreads();
    }
    if (t < NBS) boff[t] = ps[t] - v;      // exclusive
    if (t == 255) rp[N_NODES] = ps[255];   // grand total (= 800000)
}

// ---- scan phase 3: intra-block exclusive scan + block offset -> rp ----------
__global__ __launch_bounds__(256) void scan3_kernel(
    const int* __restrict__ cnt,
    const int* __restrict__ boff,
    int* __restrict__ rp)
{
    const int t = threadIdx.x;
    const int idx = blockIdx.x * 256 + t;
    const int v = (idx < N_NODES) ? cnt[idx] : 0;
    __shared__ int ps[256];
    ps[t] = v;
    __syncthreads();
    for (int off = 1; off < 256; off <<= 1) {
        const int u = (t >= off) ? ps[t - off] : 0;
        __syncthreads();
        ps[t] += u;
        __syncthreads();
    }
    if (idx < N_NODES) rp[idx] = boff[blockIdx.x] + ps[t] - v;
}

// ---- place: csr[rp[d] + (--cnt[d])] = src  (no cursor memset needed) --------
__global__ __launch_bounds__(256) void place_kernel(
    const int* __restrict__ edge_index,
    const int* __restrict__ rp,
    int* __restrict__ cnt,
    unsigned short* __restrict__ csr)
{
    const int e = blockIdx.x * 256 + threadIdx.x;          // < 800000 exact
    const int d = edge_index[N_EDGES + e];
    const int s = edge_index[e];
    const int pos = atomicSub(&cnt[d], 1) - 1;             // c-1 .. 0
    csr[rp[d] + pos] = (unsigned short)s;
}

// ---- gather: 4 nodes/wave x 16 lanes x ushort8 (full bf16 row per load) -----
__global__ __launch_bounds__(256) void gather_kernel(
    const unsigned short* __restrict__ hb,
    const int* __restrict__ rp,
    const unsigned short* __restrict__ csr,
    unsigned short* __restrict__ aggb)
{
    const int group = (threadIdx.x >> 4) & 3;
    const int sub   = threadIdx.x & 15;
    const int wave  = (blockIdx.x * 256 + threadIdx.x) >> 6;
    const int n = wave * 4 + group;
    if (n >= N_NODES) return;

    const int base = rp[n];
    const int c = rp[n + 1] - base;
    const int fo = sub * 8;

    float acc[8];
#pragma unroll
    for (int i = 0; i < 8; i++) acc[i] = 0.0f;

    int j = 0;
    for (; j + 4 <= c; j += 4) {
        const int s0 = csr[base + j],     s1 = csr[base + j + 1];
        const int s2 = csr[base + j + 2], s3 = csr[base + j + 3];
        const ushort8 v0 = *reinterpret_cast<const ushort8*>(hb + (size_t)s0 * HIDDEN + fo);
        const ushort8 v1 = *reinterpret_cast<const ushort8*>(hb + (size_t)s1 * HIDDEN + fo);
        const ushort8 v2 = *reinterpret_cast<const ushort8*>(hb + (size_t)s2 * HIDDEN + fo);
        const ushort8 v3 = *reinterpret_cast<const ushort8*>(hb + (size_t)s3 * HIDDEN + fo);
#pragma unroll
        for (int i = 0; i < 8; i++)
            acc[i] += (bf2f(v0[i]) + bf2f(v1[i])) + (bf2f(v2[i]) + bf2f(v3[i]));
    }
    for (; j < c; j++) {
        const ushort8 v0 = *reinterpret_cast<const ushort8*>(hb + (size_t)csr[base + j] * HIDDEN + fo);
#pragma unroll
        for (int i = 0; i < 8; i++) acc[i] += bf2f(v0[i]);
    }
    const float inv = 1.0f / (float)((c > 0) ? c : 1);
    ushort8 o;
#pragma unroll
    for (int i = 0; i < 8; i++) o[i] = f2bf(acc[i] * inv);
    *reinterpret_cast<ushort8*>(aggb + (size_t)n * HIDDEN + fo) = o;
}

// ---- MFMA dual GEMM + fused BN stats ----------------------------------------
// out = aggb@W_l^T + b_l + h@W_r^T.  aggb is bf16 (2 MFMAs: ahi*bhi + ahi*blo);
// h half uses split-bf16 3-product. W in LDS hi/lo, XOR slot swizzle.
__global__ __launch_bounds__(256) void gemm_kernel(
    const unsigned short* __restrict__ aggb,
    const float* __restrict__ h,
    const unsigned short* __restrict__ WhiG,   // [128][256]
    const unsigned short* __restrict__ WloG,
    const float* __restrict__ b_l,
    float* __restrict__ out,
    float* __restrict__ bn_acc)
{
    __shared__ short WsH[128][64];
    __shared__ short WsL[128][64];
    __shared__ float bnS[128];
    __shared__ float bnS2[128];

    const int tid  = threadIdx.x;
    const int lane = tid & 63;
    const int wv   = tid >> 6;
    const int row0 = blockIdx.x * 128;
    const int colb = lane & 15;
    const int quad = lane >> 4;

    if (tid < 128) { bnS[tid] = 0.0f; bnS2[tid] = 0.0f; }

    f32x4 acc[2][8];
#pragma unroll
    for (int s = 0; s < 2; s++)
#pragma unroll
        for (int c = 0; c < 8; c++) acc[s][c] = (f32x4)(0.0f);

    const int wcol  = tid >> 1;
    const int sbase = (tid & 1) * 4;

    for (int kc = 0; kc < 4; kc++) {
        const int kb = (kc & 1) * 64;
        const int kw = kc * 64;

        __syncthreads();
#pragma unroll
        for (int j = 0; j < 4; j++) {
            const int slot = sbase + j;
            short8 vh = *reinterpret_cast<const short8*>(WhiG + (size_t)wcol * 256 + kw + slot * 8);
            short8 vl = *reinterpret_cast<const short8*>(WloG + (size_t)wcol * 256 + kw + slot * 8);
            const int sp = slot ^ (wcol & 7);
            *reinterpret_cast<short8*>(&WsH[wcol][sp * 8]) = vh;
            *reinterpret_cast<short8*>(&WsL[wcol][sp * 8]) = vl;
        }
        __syncthreads();

#pragma unroll
        for (int ks = 0; ks < 2; ks++) {
            short8 ahi[2], alo[2];
#pragma unroll
            for (int sub = 0; sub < 2; sub++) {
                int row = row0 + wv * 32 + sub * 16 + colb;
                row = (row < N_NODES) ? row : (N_NODES - 1);
                if (kc < 2) {
                    ahi[sub] = *reinterpret_cast<const short8*>(
                        aggb + (size_t)row * HIDDEN + kb + ks * 32 + quad * 8);
                } else {
                    const float* xp = h + (size_t)row * HIDDEN + kb + ks * 32 + quad * 8;
                    float xr[8];
                    const float4 p0 = *reinterpret_cast<const float4*>(xp);
                    const float4 p1 = *reinterpret_cast<const float4*>(xp + 4);
                    xr[0] = p0.x; xr[1] = p0.y; xr[2] = p0.z; xr[3] = p0.w;
                    xr[4] = p1.x; xr[5] = p1.y; xr[6] = p1.z; xr[7] = p1.w;
                    cvt8(xr, ahi[sub], alo[sub]);
                }
            }
#pragma unroll
            for (int c = 0; c < 8; c++) {
                const int bc = c * 16 + colb;
                const int sp = (ks * 4 + quad) ^ (bc & 7);
                short8 bhi = *reinterpret_cast<const short8*>(&WsH[bc][sp * 8]);
                short8 blo = *reinterpret_cast<const short8*>(&WsL[bc][sp * 8]);
#pragma unroll
                for (int sub = 0; sub < 2; sub++) {
                    acc[sub][c] = __builtin_amdgcn_mfma_f32_16x16x32_bf16(ahi[sub], bhi, acc[sub][c], 0, 0, 0);
                    acc[sub][c] = __builtin_amdgcn_mfma_f32_16x16x32_bf16(ahi[sub], blo, acc[sub][c], 0, 0, 0);
                    if (kc >= 2)
                        acc[sub][c] = __builtin_amdgcn_mfma_f32_16x16x32_bf16(alo[sub], bhi, acc[sub][c], 0, 0, 0);
                }
            }
        }
    }

#pragma unroll
    for (int c = 0; c < 8; c++) {
        const int col = c * 16 + colb;
        const float bias = b_l[col];
        float s = 0.0f, s2 = 0.0f;
#pragma unroll
        for (int sub = 0; sub < 2; sub++) {
            const int rbase = row0 + wv * 32 + sub * 16 + quad * 4;
#pragma unroll
            for (int reg = 0; reg < 4; reg++) {
                const int r = rbase + reg;
                if (r < N_NODES) {
                    const float o = acc[sub][c][reg] + bias;
                    out[(size_t)r * HIDDEN + col] = o;
                    s += o; s2 += o * o;
                }
            }
        }
        atomicAdd(&bnS[col], s);
        atomicAdd(&bnS2[col], s2);
    }
    __syncthreads();
    if (tid < 128) {
        atomicAdd(&bn_acc[tid], bnS[tid]);
        atomicAdd(&bn_acc[128 + tid], bnS2[tid]);
    }
}

// ---- BN apply + ReLU + residual ----
__global__ __launch_bounds__(256) void bn_apply_kernel(
    const float* __restrict__ h,
    const float* __restrict__ gamma,
    const float* __restrict__ beta,
    const float* __restrict__ bn_acc,
    float* __restrict__ out)
{
    const float inv_n = 1.0f / (float)N_NODES;
    const size_t total = (size_t)N_NODES * HIDDEN;
    size_t idx = ((size_t)blockIdx.x * blockDim.x + threadIdx.x) * 4;
    const size_t stride = (size_t)gridDim.x * blockDim.x * 4;

    for (; idx < total; idx += stride) {
        const int col = (int)(idx & (HIDDEN - 1));
        float4 x  = *reinterpret_cast<float4*>(out + idx);
        float4 sm = *reinterpret_cast<const float4*>(bn_acc + col);
        float4 sq = *reinterpret_cast<const float4*>(bn_acc + HIDDEN + col);
        float4 g  = *reinterpret_cast<const float4*>(gamma + col);
        float4 bt = *reinterpret_cast<const float4*>(beta + col);
        float4 hr = *reinterpret_cast<const float4*>(h + idx);

        float4 res;
        {
            float m = sm.x * inv_n; float var = sq.x * inv_n - m * m;
            float v = g.x * (x.x - m) * rsqrtf(var + BN_EPS) + bt.x;
            res.x = fmaxf(v, 0.0f) + hr.x;
        }
        {
            float m = sm.y * inv_n; float var = sq.y * inv_n - m * m;
            float v = g.y * (x.y - m) * rsqrtf(var + BN_EPS) + bt.y;
            res.y = fmaxf(v, 0.0f) + hr.y;
        }
        {
            float m = sm.z * inv_n; float var = sq.z * inv_n - m * m;
            float v = g.z * (x.z - m) * rsqrtf(var + BN_EPS) + bt.z;
            res.z = fmaxf(v, 0.0f) + hr.z;
        }
        {
            float m = sm.w * inv_n; float var = sq.w * inv_n - m * m;
            float v = g.w * (x.w - m) * rsqrtf(var + BN_EPS) + bt.w;
            res.w = fmaxf(v, 0.0f) + hr.w;
        }
        *reinterpret_cast<float4*>(out + idx) = res;
    }
}

extern "C" void kernel_launch(void* const* d_in, const int* in_sizes, int n_in,
                              void* d_out, int out_size, void* d_ws, size_t ws_size,
                              hipStream_t stream)
{
    const float* h          = (const float*)d_in[0];
    const int*   edge_index = (const int*)d_in[1];
    const float* W_l        = (const float*)d_in[2];
    const float* b_l        = (const float*)d_in[3];
    const float* W_r        = (const float*)d_in[4];
    const float* gamma      = (const float*)d_in[5];
    const float* beta       = (const float*)d_in[6];
    float* out = (float*)d_out;

    char* ws = (char*)d_ws;                                 // all 16B-aligned segments
    int* cnt  = (int*)ws;                                   // 50000
    int* rp   = cnt + 50000;                                // 50004 (uses 50001)
    int* bsum = rp + 50004;                                 // 256
    int* boff = bsum + 256;                                 // 256
    unsigned short* csr  = (unsigned short*)(boff + 256);   // 800000
    unsigned short* hb   = csr + 800000;                    // 6,400,000
    unsigned short* aggb = hb + 6400000;                    // 6,400,000
    unsigned short* WhiG = aggb + 6400000;                  // 32768
    unsigned short* WloG = WhiG + 32768;                    // 32768
    float* bn_acc = (float*)(WloG + 32768);                 // 256

    hipMemsetAsync(cnt, 0, 50000 * sizeof(int), stream);

    prep_kernel<<<NB_EDGE + NB_HB + NB_W, 256, 0, stream>>>(
        edge_index, h, W_l, W_r, cnt, hb, WhiG, WloG, bn_acc);

    scan1_kernel<<<NBS, 256, 0, stream>>>(cnt, bsum);
    scan2_kernel<<<1, 256, 0, stream>>>(bsum, boff, rp);
    scan3_kernel<<<NBS, 256, 0, stream>>>(cnt, boff, rp);

    place_kernel<<<NB_EDGE, 256, 0, stream>>>(edge_index, rp, cnt, csr);

    gather_kernel<<<(N_NODES / 4 + 3) / 4, 256, 0, stream>>>(hb, rp, csr, aggb);

    gemm_kernel<<<(N_NODES + 127) / 128, 256, 0, stream>>>(
        aggb, h, WhiG, WloG, b_l, out, bn_acc);

    bn_apply_kernel<<<2048, 256, 0, stream>>>(h, gamma, beta, bn_acc, out);
}